// Round 11
// baseline (102.320 us; speedup 1.0000x reference)
//
#include <hip/hip_runtime.h>
#include <hip/hip_bf16.h>

// out = softmax((X Wq + bq)(X Wk + bk)^T / 8) (X Wv + bv) Wo + bo
// All prune/straight-through ops in the reference are value-wise identity.
//
// Strategy this round: BARRIER-FREE GEMMs. A and W are pre-packed into
// MFMA-fragment-major layout (frag (g=lane>>4,c=lane&15) holds X[row=c][k=g*8..+7]
// per 16x32 tile -> 1KB contiguous per fragment). Each wave computes an
// independent 64x64 output tile: 24 K-steps of {8 coalesced 16B loads + 16 MFMA},
// software-pipelined, no __syncthreads, no LDS in the K-loop. Latency hidden by
// TLP (2664 independent waves, ~3 waves/SIMD resident).
//   k_prep : hs -> ablk (fragment-major, zero-padded), W -> wblk/oblk
//            (fragment-major), kh/vt pad zeroing
//   k_qkv  : fused QKV, per-wave 64x64, epilogue via per-wave LDS -> 16B stores
//   k_attn : unchanged (round-6 proven flash attention)
//   k_oproj: out-proj, A-frags read row-major from ctx, W from oblk, fp32 out

#define B_ 8
#define S_ 577
#define H_ 768
#define NH_ 12
#define HD_ 64
#define M_ (B_*S_)     /* 4616 */
#define MPAD 4736
#define BH_ (B_*NH_)   /* 96 */
#define SKPAD 640      /* padded key count */
#define KT_ 24         /* 768/32 K-fragments */

typedef __attribute__((ext_vector_type(8))) short short8;
typedef __attribute__((ext_vector_type(4))) short s16x4;
typedef __attribute__((ext_vector_type(4))) float f32x4;

__device__ inline unsigned short f2bf(float f){
    unsigned int u = __float_as_uint(f);
    u = u + 0x7fffu + ((u>>16)&1u);     // round-to-nearest-even
    return (unsigned short)(u>>16);
}

__device__ inline void gload_lds16(const short* g, short* l){
    __builtin_amdgcn_global_load_lds((const __attribute__((address_space(1))) void*)g,
                                     (__attribute__((address_space(3))) void*)l, 16, 0, 0);
}

// fused prep: blocks [0,1776) cvt->ablk | [1776,2352) W->wblk/oblk | [2352,2733) pad
__global__ __launch_bounds__(256) void k_prep(
    const float* __restrict__ hs, short* __restrict__ ablk,
    const float* __restrict__ Wq, const float* __restrict__ Wk,
    const float* __restrict__ Wv, const float* __restrict__ Wo,
    short* __restrict__ wblk, short* __restrict__ oblk,
    short* __restrict__ kh, short* __restrict__ vt)
{
    const int bid = blockIdx.x, t = threadIdx.x;
    if(bid < 1776){
        // chunk i covers hs row=i/96, k8=(i%96): 8 consecutive k of one row
        int i = bid*256 + t;
        int row = i/96, k8 = i - row*96;
        // fragment-major dest: [mi=row>>4][kt=k8>>2][lane=(k8&3)*16 + (row&15)][8]
        size_t dst = ((size_t)((row>>4)*KT_ + (k8>>2))*64 + (k8&3)*16 + (row&15))*8;
        if(bid >= 1731){ *(short8*)(ablk + dst) = (short8){}; return; }   // rows>=4616 zero
        const float4* p = (const float4*)(hs + (size_t)i*8);
        float4 a = p[0], b = p[1];
        short8 v;
        v[0]=(short)f2bf(a.x); v[1]=(short)f2bf(a.y); v[2]=(short)f2bf(a.z); v[3]=(short)f2bf(a.w);
        v[4]=(short)f2bf(b.x); v[5]=(short)f2bf(b.y); v[6]=(short)f2bf(b.z); v[7]=(short)f2bf(b.w);
        *(short8*)(ablk + dst) = v;
    } else if(bid < 2352){
        // W [k][n] fp32 -> fragment-major B^T blocks
        int zidx = bid - 1776;
        int z = zidx & 3, rem = zidx >> 2;
        int kx = rem % 12, ny = rem / 12;
        const float* W = z==0?Wq: z==1?Wk: z==2?Wv:Wo;
        short* Dst = (z<3)? wblk : oblk;
        __shared__ float lds[64][65];
        int k0 = kx*64, n0 = ny*64;
        for(int i=0;i<4;i++){
            int row = i*16 + (t>>4);
            int col = (t&15)*4;
            float4 v = *(const float4*)&W[(k0+row)*768 + n0 + col];
            lds[row][col]=v.x; lds[row][col+1]=v.y; lds[row][col+2]=v.z; lds[row][col+3]=v.w;
        }
        __syncthreads();
        #pragma unroll
        for(int rep=0; rep<2; rep++){
            int n_loc = (t>>3) + rep*32;
            int k8 = t&7;                       // 8-k chunk within 64
            short8 v;
            #pragma unroll
            for(int j=0;j<8;j++) v[j] = (short)f2bf(lds[k8*8+j][n_loc]);
            int nf = (z<3 ? z*768 : 0) + n0 + n_loc;
            size_t dst = ((size_t)((nf>>4)*KT_ + (k0>>5) + (k8>>2))*64 + (k8&3)*16 + (nf&15))*8;
            *(short8*)(Dst + dst) = v;
        }
    } else {
        int tid = (bid-2352)*256 + t;
        short8 z = {};
        if(tid < 48384){
            int row_id = tid>>3, ch = tid&7;
            int bh = row_id/63, r = row_id - bh*63;
            *(short8*)&kh[((size_t)bh*SKPAD + 577 + r)*64 + ch*8] = z;
        } else if(tid < 97536){
            int j = tid - 48384;
            int row_id = j>>3, ch = j&7;
            int bh = row_id>>6, d = row_id&63;
            *(short8*)&vt[((size_t)bh*64 + d)*SKPAD + 576 + ch*8] = z;
        }
    }
}

// -------- fused QKV GEMM: per-wave independent 64x64 tiles, no barriers --------
__global__ __launch_bounds__(256,3) void k_qkv(
    const short* __restrict__ ablk, const short* __restrict__ wblk,
    const float* __restrict__ b0, const float* __restrict__ b1, const float* __restrict__ b2,
    short* __restrict__ oq, short* __restrict__ ok, short* __restrict__ ovt)
{
    __shared__ short sh[4*64*72];          // per-wave epilogue staging
    const int t = threadIdx.x;
    const int w = t>>6, lane = t&63, g = lane>>4, c = lane&15;

    // bijective XCD-chunked block swizzle
    const int nwg = gridDim.x;              // 666
    const int q8 = nwg>>3, r8 = nwg&7;
    const int xcd = blockIdx.x&7, cidx = blockIdx.x>>3;
    const int wg = (xcd<r8 ? xcd*(q8+1) : r8*(q8+1) + (xcd-r8)*q8) + cidx;
    const int gw = wg*4 + w;                // global wave id, < 2664
    const int mtile = gw/36, ntile = gw - mtile*36;
    const int seg = ntile/12;
    const int nl64 = (ntile - seg*12)*64;   // col base within segment [0,768)
    const float* bias = (seg==0?b0: seg==1?b1:b2);

    const short* pa = ablk + ((size_t)(mtile*4)*KT_)*512 + lane*8;
    const short* pw = wblk + ((size_t)(ntile*4)*KT_)*512 + lane*8;

    f32x4 acc[4][4] = {};
    short8 a0[4], bf0[4], a1[4], bf1[4];

    #define LD(AA,BB,kt) { _Pragma("unroll") for(int x=0;x<4;x++){            \
        AA[x] = *(const short8*)(pa + ((size_t)x*KT_ + (kt))*512);            \
        BB[x] = *(const short8*)(pw + ((size_t)x*KT_ + (kt))*512); } }
    #define FM(AA,BB) { _Pragma("unroll") for(int mi=0;mi<4;mi++)             \
        _Pragma("unroll") for(int ni=0;ni<4;ni++)                             \
        acc[mi][ni] = __builtin_amdgcn_mfma_f32_16x16x32_bf16(AA[mi], BB[ni], acc[mi][ni],0,0,0); }

    LD(a0,bf0,0);
    #pragma unroll 1
    for(int it=0; it<11; it++){
        LD(a1,bf1, 2*it+1);
        FM(a0,bf0);
        LD(a0,bf0, 2*it+2);
        FM(a1,bf1);
    }
    LD(a1,bf1, 23);
    FM(a0,bf0);
    FM(a1,bf1);
    #undef LD
    #undef FM

    // epilogue: per-wave LDS staging -> coalesced 16B stores
    short* my = sh + w*4608;                // [64][72]
    const int h = nl64>>6;                  // one head per wave tile
    const int m0 = mtile*64;
    if(seg==2){
        // V transposed: [d][m]
        #pragma unroll
        for(int mi=0;mi<4;mi++)
            #pragma unroll
            for(int ni=0;ni<4;ni++){
                int nl_ = ni*16 + c;
                float bv = bias[nl64 + nl_];
                s16x4 pk;
                #pragma unroll
                for(int r=0;r<4;r++) pk[r] = (short)f2bf(acc[mi][ni][r] + bv);
                *(s16x4*)&my[nl_*72 + mi*16 + g*4] = pk;
            }
    } else {
        #pragma unroll
        for(int mi=0;mi<4;mi++)
            #pragma unroll
            for(int ni=0;ni<4;ni++){
                int nl_ = ni*16 + c;
                float bv = bias[nl64 + nl_];
                #pragma unroll
                for(int r=0;r<4;r++)
                    my[(mi*16+g*4+r)*72 + nl_] = (short)f2bf(acc[mi][ni][r] + bv);
            }
    }
    asm volatile("s_waitcnt lgkmcnt(0)" ::: "memory");

    const int lr8 = lane>>3, lch = lane&7;
    if(seg==2){
        #pragma unroll
        for(int j=0;j<8;j++){
            int d = j*8 + lr8;
            short8 v8 = *(const short8*)&my[d*72 + lch*8];
            int mg = m0 + lch*8;
            if(mg < M_){
                int bb = mg/S_, s0 = mg - bb*S_;
                if(s0+7 < S_ && mg+7 < M_){
                    *(short8*)&ovt[(((size_t)bb*NH_+h)*HD_+d)*SKPAD + s0] = v8;
                } else {
                    for(int jj=0;jj<8;jj++){
                        int m=mg+jj;
                        if(m<M_){ int bj=m/S_, sj=m-bj*S_;
                            ovt[(((size_t)bj*NH_+h)*HD_+d)*SKPAD+sj]=v8[jj]; }
                    }
                }
            }
        }
    } else {
        #pragma unroll
        for(int j=0;j<8;j++){
            int m = m0 + j*8 + lr8;
            if(m < M_){
                short8 v8 = *(const short8*)&my[(j*8+lr8)*72 + lch*8];
                int bb = m/S_, ss = m - bb*S_;
                if(seg==1) *(short8*)&ok[(((size_t)bb*NH_+h)*SKPAD + ss)*HD_ + lch*8] = v8;
                else       *(short8*)&oq[(((size_t)bb*NH_+h)*S_   + ss)*HD_ + lch*8] = v8;
            }
        }
    }
}

// -------- out-proj: per-wave 64x64, A row-major from ctx, W fragment-major ----
__global__ __launch_bounds__(256,3) void k_oproj(
    const short* __restrict__ ctx, const short* __restrict__ oblk,
    const float* __restrict__ bo, float* __restrict__ of)
{
    const int t = threadIdx.x;
    const int w = t>>6, lane = t&63, g = lane>>4, c = lane&15;

    const int nwg = gridDim.x;              // 222
    const int q8 = nwg>>3, r8 = nwg&7;
    const int xcd = blockIdx.x&7, cidx = blockIdx.x>>3;
    const int wg = (xcd<r8 ? xcd*(q8+1) : r8*(q8+1) + (xcd-r8)*q8) + cidx;
    const int gw = wg*4 + w;                // < 888
    const int mtile = gw/12, ntile = gw - mtile*12;
    const int m0 = mtile*64, n0 = ntile*64;

    const short* pa = ctx + (size_t)(m0 + c)*768 + g*8;
    const short* pw = oblk + ((size_t)(ntile*4)*KT_)*512 + lane*8;

    f32x4 acc[4][4] = {};
    short8 a0[4], bf0[4], a1[4], bf1[4];

    #define LD(AA,BB,kt) { _Pragma("unroll") for(int x=0;x<4;x++){            \
        AA[x] = *(const short8*)(pa + (size_t)x*16*768 + (kt)*32);            \
        BB[x] = *(const short8*)(pw + ((size_t)x*KT_ + (kt))*512); } }
    #define FM(AA,BB) { _Pragma("unroll") for(int mi=0;mi<4;mi++)             \
        _Pragma("unroll") for(int ni=0;ni<4;ni++)                             \
        acc[mi][ni] = __builtin_amdgcn_mfma_f32_16x16x32_bf16(AA[mi], BB[ni], acc[mi][ni],0,0,0); }

    LD(a0,bf0,0);
    #pragma unroll 1
    for(int it=0; it<11; it++){
        LD(a1,bf1, 2*it+1);
        FM(a0,bf0);
        LD(a0,bf0, 2*it+2);
        FM(a1,bf1);
    }
    LD(a1,bf1, 23);
    FM(a0,bf0);
    FM(a1,bf1);
    #undef LD
    #undef FM

    #pragma unroll
    for(int mi=0; mi<4; mi++)
        #pragma unroll
        for(int ni=0; ni<4; ni++){
            #pragma unroll
            for(int r=0; r<4; r++){
                int m = m0 + mi*16 + g*4 + r;
                int n = n0 + ni*16 + c;
                if(m >= M_) continue;
                of[(size_t)m*768 + n] = acc[mi][ni][r] + bo[n];
            }
        }
}

// flash attention (round-6 proven): QBLK=128, K/V dbuf counted vmcnt, setprio
__global__ __launch_bounds__(256) void k_attn(
    const short* __restrict__ qh, const short* __restrict__ kh, const short* __restrict__ vt,
    short* __restrict__ ctx)
{
    __shared__ short lK[2][64*64], lV[2][64*64], lP[4*2048];
    const int t = threadIdx.x;
    const int w = t>>6, lane = t&63, g = lane>>4, c = lane&15;
    const int bh = blockIdx.x, b = bh/NH_, h = bh%NH_;
    const int q0 = blockIdx.y*128;

    #pragma unroll
    for(int i=0;i<4;i++){
        int row = i*8 + (lane>>3);
        int e8 = (lane&7)*8;
        int s = q0 + w*32 + row;
        short8 v = {};
        if(s < S_) v = *(const short8*)&qh[((size_t)bh*S_ + s)*HD_ + e8];
        *(short8*)&lP[w*2048 + row*64 + (e8 ^ ((row&7)<<3))] = v;
    }
    short8 qf[2][2];
    #pragma unroll
    for(int qi=0; qi<2; qi++)
        #pragma unroll
        for(int ks=0; ks<2; ks++)
            qf[qi][ks] = *(const short8*)&lP[w*2048 + (qi*16+c)*64 + ((ks*32+g*8) ^ ((c&7)<<3))];

    short8 ones;
    #pragma unroll
    for(int j=0;j<8;j++) ones[j] = (short)0x3F80;

    const int srow = lane>>3;
    const int sw8 = ((lane&7) ^ srow)*8;
    const short* pk0 = kh + ((size_t)bh*SKPAD + w*16 + srow)*64 + sw8;
    const short* pv0 = vt + ((size_t)bh*64 + w*16 + srow)*SKPAD + sw8;

    #pragma unroll
    for(int i=0;i<2;i++){
        gload_lds16(pk0 + i*8*64,    &lK[0][(w*16+i*8)*64]);
        gload_lds16(pv0 + i*8*SKPAD, &lV[0][(w*16+i*8)*64]);
    }

    float m_run[2][4], l_run[2][4];
    f32x4 O[2][4] = {};
    #pragma unroll
    for(int qi=0;qi<2;qi++)
        #pragma unroll
        for(int r=0;r<4;r++){ m_run[qi][r] = -3e38f; l_run[qi][r] = 0.f; }

    int bb = 0;
    for(int kt=0; kt<10; kt++){
        if(kt<9){
            const short* pk = pk0 + (kt+1)*4096;
            const short* pv = pv0 + (kt+1)*64;
            #pragma unroll
            for(int i=0;i<2;i++){
                gload_lds16(pk + i*8*64,    &lK[bb^1][(w*16+i*8)*64]);
                gload_lds16(pv + i*8*SKPAD, &lV[bb^1][(w*16+i*8)*64]);
            }
            asm volatile("s_waitcnt vmcnt(4)" ::: "memory");
        } else {
            asm volatile("s_waitcnt vmcnt(0)" ::: "memory");
        }
        __builtin_amdgcn_s_barrier();
        asm volatile("" ::: "memory");

        const short* LK = lK[bb]; const short* LV = lV[bb];

        float sv[2][4][4];
        #pragma unroll
        for(int nt=0; nt<4; nt++){
            int row = nt*16 + c;
            int rx = (row&7)<<3;
            short8 kf[2];
            kf[0] = *(const short8*)&LK[row*64 + ((g*8) ^ rx)];
            kf[1] = *(const short8*)&LK[row*64 + ((32+g*8) ^ rx)];
            __builtin_amdgcn_s_setprio(1);
            #pragma unroll
            for(int qi=0; qi<2; qi++){
                f32x4 sa = {};
                sa = __builtin_amdgcn_mfma_f32_16x16x32_bf16(qf[qi][0], kf[0], sa, 0,0,0);
                sa = __builtin_amdgcn_mfma_f32_16x16x32_bf16(qf[qi][1], kf[1], sa, 0,0,0);
                #pragma unroll
                for(int r=0;r<4;r++) sv[qi][nt][r] = sa[r]*0.18033688011f;
            }
            __builtin_amdgcn_s_setprio(0);
        }
        if(kt==9){
            #pragma unroll
            for(int nt=0; nt<4; nt++){
                int key = 576 + nt*16 + c;
                if(key >= S_){
                    #pragma unroll
                    for(int qi=0;qi<2;qi++)
                        #pragma unroll
                        for(int r=0;r<4;r++) sv[qi][nt][r] = -3e38f;
                }
            }
        }
        float fac[2][4];
        #pragma unroll
        for(int qi=0; qi<2; qi++)
            #pragma unroll
            for(int r=0;r<4;r++){
                float mx = fmaxf(fmaxf(sv[qi][0][r],sv[qi][1][r]),fmaxf(sv[qi][2][r],sv[qi][3][r]));
                for(int off=1; off<16; off<<=1) mx = fmaxf(mx, __shfl_xor(mx, off));
                float nm = fmaxf(m_run[qi][r], mx);
                fac[qi][r] = __builtin_amdgcn_exp2f(m_run[qi][r] - nm);
                m_run[qi][r] = nm;
            }
        #pragma unroll
        for(int qi=0; qi<2; qi++)
            #pragma unroll
            for(int nt=0; nt<4; nt++)
                #pragma unroll
                for(int r=0;r<4;r++){
                    float p = __builtin_amdgcn_exp2f(sv[qi][nt][r] - m_run[qi][r]);
                    int prow = g*4 + r;
                    lP[w*2048 + qi*1024 + prow*64 + ((nt*16 + c) ^ ((prow&7)<<3))] = (short)f2bf(p);
                }
        short8 pf[2][2];
        #pragma unroll
        for(int qi=0; qi<2; qi++)
            #pragma unroll
            for(int ks=0; ks<2; ks++)
                pf[qi][ks] = *(const short8*)&lP[w*2048 + qi*1024 + c*64 + ((ks*32+g*8) ^ ((c&7)<<3))];
        __builtin_amdgcn_s_setprio(1);
        #pragma unroll
        for(int qi=0; qi<2; qi++){
            f32x4 rs = {};
            rs = __builtin_amdgcn_mfma_f32_16x16x32_bf16(pf[qi][0], ones, rs, 0,0,0);
            rs = __builtin_amdgcn_mfma_f32_16x16x32_bf16(pf[qi][1], ones, rs, 0,0,0);
            #pragma unroll
            for(int r=0;r<4;r++) l_run[qi][r] = l_run[qi][r]*fac[qi][r] + rs[r];
        }
        __builtin_amdgcn_s_setprio(0);
        #pragma unroll
        for(int qi=0; qi<2; qi++)
            #pragma unroll
            for(int nt=0;nt<4;nt++)
                #pragma unroll
                for(int r=0;r<4;r++) O[qi][nt][r] *= fac[qi][r];

        __builtin_amdgcn_s_setprio(1);
        #pragma unroll
        for(int nt=0; nt<4; nt++){
            int vrow = nt*16 + c;
            int rx = (vrow&7)<<3;
            short8 vf[2];
            vf[0] = *(const short8*)&LV[vrow*64 + ((g*8) ^ rx)];
            vf[1] = *(const short8*)&LV[vrow*64 + ((32+g*8) ^ rx)];
            #pragma unroll
            for(int qi=0; qi<2; qi++){
                O[qi][nt] = __builtin_amdgcn_mfma_f32_16x16x32_bf16(pf[qi][0], vf[0], O[qi][nt], 0,0,0);
                O[qi][nt] = __builtin_amdgcn_mfma_f32_16x16x32_bf16(pf[qi][1], vf[1], O[qi][nt], 0,0,0);
            }
        }
        __builtin_amdgcn_s_setprio(0);
        asm volatile("s_waitcnt lgkmcnt(0)" ::: "memory");
        __builtin_amdgcn_s_barrier();
        asm volatile("" ::: "memory");
        bb ^= 1;
    }

    #pragma unroll
    for(int qi=0; qi<2; qi++)
        #pragma unroll
        for(int nt=0; nt<4; nt++)
            #pragma unroll
            for(int r=0;r<4;r++){
                int s = q0 + w*32 + qi*16 + g*4 + r;
                if(s < S_){
                    float val = O[qi][nt][r] / l_run[qi][r];
                    ctx[((size_t)b*S_ + s)*H_ + h*HD_ + nt*16 + c] = (short)f2bf(val);
                }
            }
}

extern "C" void kernel_launch(void* const* d_in, const int* in_sizes, int n_in,
                              void* d_out, int out_size, void* d_ws, size_t ws_size,
                              hipStream_t stream)
{
    const float* hs = (const float*)d_in[0];
    const float* Wq = (const float*)d_in[1];
    const float* bq = (const float*)d_in[2];
    const float* Wk = (const float*)d_in[3];
    const float* bk = (const float*)d_in[4];
    const float* Wv = (const float*)d_in[5];
    const float* bv = (const float*)d_in[6];
    const float* Wo = (const float*)d_in[7];
    const float* bo = (const float*)d_in[8];
    float* out = (float*)d_out;

    char* ws = (char*)d_ws;
    // ablk: 296*24*1024 = 7,274,496 (fragment-major A; reused as row-major ctx)
    // wblk: 144*24*1024 = 3,538,944 ; oblk: 48*24*1024 = 1,179,648
    // qh: 7,090,176 ; kh: 7,864,320 ; vt: 7,864,320  -> total 34,811,904
    short* ablk = (short*)(ws);
    short* ctx  = ablk;                             // reuse after QKV GEMM
    short* wblk = (short*)(ws + 7274496);
    short* oblk = (short*)(ws + 10813440);
    short* qh   = (short*)(ws + 11993088);
    short* kh   = (short*)(ws + 19083264);
    short* vt   = (short*)(ws + 26947584);

    k_prep<<<2733, 256, 0, stream>>>(hs, ablk, Wq,Wk,Wv,Wo, wblk, oblk, kh, vt);
    k_qkv<<<666, 256, 0, stream>>>(ablk, wblk, bq,bk,bv, qh,kh,vt);
    k_attn<<<dim3(96,5), 256, 0, stream>>>(qh, kh, vt, ctx);
    k_oproj<<<222, 256, 0, stream>>>(ctx, oblk, bo, out);
}

// Round 12
// 102.316 us; speedup vs baseline: 1.0000x; 1.0000x over previous
//
#include <hip/hip_runtime.h>
#include <hip/hip_bf16.h>

// out = softmax((X Wq + bq)(X Wk + bk)^T / 8) (X Wv + bv) Wo + bo
// All prune/straight-through ops in the reference are value-wise identity.
//
// Pipeline (all bf16 MFMA 16x16x32, fp32 accum):
//   k_prep: fused {hs->bf16 A [4736][768] w/ zero pad | W^T bf16 x4 | kh/vt pad zero}
//   k_gemm: fused QKV GEMM (N=2304), 128x128 tile, 512 threads (8 waves),
//           double-buffered gload_lds with counted vmcnt(4), XCD-chunked swizzle;
//           LDS-staged coalesced epilogue (V transposed). mode 3 = ctx@Wo+bo.
//           (best-measured structure: round-6, 91.9 us total)
//   k_attn: BARRIER-FREE flash attention. K/V fragments loaded directly from
//           global (L1/L2-resident: 160KB/head, 5 q-blocks/head share via XCD
//           pinning, 4 waves/block share via L1). No __syncthreads in the kt
//           loop; P through per-wave LDS region (lgkmcnt only). Wave-slip TLP
//           hides latency; compiler's vmcnt pipelines V-loads under softmax.

#define B_ 8
#define S_ 577
#define H_ 768
#define NH_ 12
#define HD_ 64
#define M_ (B_*S_)     /* 4616 */
#define MPAD 4736
#define BH_ (B_*NH_)   /* 96 */
#define SKPAD 640      /* padded key count */
#define LTS 136        /* padded LDS row stride (shorts) for epilogue tile */

typedef __attribute__((ext_vector_type(8))) short short8;
typedef __attribute__((ext_vector_type(4))) short s16x4;
typedef __attribute__((ext_vector_type(4))) float f32x4;

__device__ inline unsigned short f2bf(float f){
    unsigned int u = __float_as_uint(f);
    u = u + 0x7fffu + ((u>>16)&1u);     // round-to-nearest-even
    return (unsigned short)(u>>16);
}

__device__ inline void gload_lds16(const short* g, short* l){
    __builtin_amdgcn_global_load_lds((const __attribute__((address_space(1))) void*)g,
                                     (__attribute__((address_space(3))) void*)l, 16, 0, 0);
}

// fused prep: blocks [0,1776) cvt | [1776,2352) wt | [2352,2733) pad
__global__ __launch_bounds__(256) void k_prep(
    const float* __restrict__ hs, short* __restrict__ abf,
    const float* __restrict__ Wq, const float* __restrict__ Wk,
    const float* __restrict__ Wv, const float* __restrict__ Wo,
    short* __restrict__ Tq, short* __restrict__ Tk,
    short* __restrict__ Tv, short* __restrict__ To,
    short* __restrict__ kh, short* __restrict__ vt)
{
    const int bid = blockIdx.x, t = threadIdx.x;
    if(bid < 1776){
        int i = bid*256 + t;
        if(bid >= 1731){ *(short8*)(abf + (size_t)i*8) = (short8){}; return; }
        const float4* p = (const float4*)(hs + (size_t)i*8);
        float4 a = p[0], b = p[1];
        short8 v;
        v[0]=(short)f2bf(a.x); v[1]=(short)f2bf(a.y); v[2]=(short)f2bf(a.z); v[3]=(short)f2bf(a.w);
        v[4]=(short)f2bf(b.x); v[5]=(short)f2bf(b.y); v[6]=(short)f2bf(b.z); v[7]=(short)f2bf(b.w);
        *(short8*)(abf + (size_t)i*8) = v;
    } else if(bid < 2352){
        int zidx = bid - 1776;
        int z = zidx & 3, rem = zidx >> 2;
        int kx = rem % 12, ny = rem / 12;
        const float* W = z==0?Wq: z==1?Wk: z==2?Wv:Wo;
        short*       T = z==0?Tq: z==1?Tk: z==2?Tv:To;
        __shared__ float lds[64][65];
        int k0 = kx*64, n0 = ny*64;
        for(int i=0;i<4;i++){
            int row = i*16 + (t>>4);
            int col = (t&15)*4;
            float4 v = *(const float4*)&W[(k0+row)*768 + n0 + col];
            lds[row][col]=v.x; lds[row][col+1]=v.y; lds[row][col+2]=v.z; lds[row][col+3]=v.w;
        }
        __syncthreads();
        for(int i=0;i<4;i++){
            int n = i*16 + (t>>4);
            int k4 = (t&15)*4;
            for(int j=0;j<4;j++)
                T[(n0+n)*768 + k0 + k4 + j] = (short)f2bf(lds[k4+j][n]);
        }
    } else {
        int tid = (bid-2352)*256 + t;
        short8 z = {};
        if(tid < 48384){
            int row_id = tid>>3, ch = tid&7;
            int bh = row_id/63, r = row_id - bh*63;
            *(short8*)&kh[((size_t)bh*SKPAD + 577 + r)*64 + ch*8] = z;
        } else if(tid < 97536){
            int j = tid - 48384;
            int row_id = j>>3, ch = j&7;
            int bh = row_id>>6, d = row_id&63;
            *(short8*)&vt[((size_t)bh*64 + d)*SKPAD + 576 + ch*8] = z;
        }
    }
}

// 128x128 tile GEMM, 512 threads / 8 waves, double-buffered counted-vmcnt K-loop,
// XCD-chunked swizzle. mode 0: QKV fused; mode 3: ctx@Wo+bo -> fp32
__global__ __launch_bounds__(512) void k_gemm(
    const short* __restrict__ A, const short* __restrict__ T,
    const float* __restrict__ b0, const float* __restrict__ b1, const float* __restrict__ b2,
    short* __restrict__ oq, short* __restrict__ ok, short* __restrict__ ovt,
    float* __restrict__ of, int mode, int NT)
{
    __shared__ short sh[32768];            // 64KB: dbuf K-loop; epilogue reuses [0,17408)
    const int t = threadIdx.x;

    const int nwg = gridDim.x;
    const int q8 = nwg>>3, r8 = nwg&7;
    const int xcd = blockIdx.x&7, cidx = blockIdx.x>>3;
    const int wg = (xcd<r8 ? xcd*(q8+1) : r8*(q8+1) + (xcd-r8)*q8) + cidx;
    const int mt = wg/NT, ntile = wg - mt*NT;
    const int m0 = mt*128, n0 = ntile*128;

    const int seg = (mode==3)? 0 : n0/768;
    const float* bias = (mode==3)? b0 : (seg==0?b0: seg==1?b1:b2);
    const int nlb = (mode==3)? n0 : n0 - seg*768;

    const int w = t>>6, lane = t&63, g = lane>>4, c = lane&15;
    const int wm = w>>1, wn = w&1;

    const int lrow = lane>>3;
    const int lcol = ((lane&7) ^ lrow) * 8;
    const short* pa = A + (size_t)(m0 + w*8 + lrow)*768 + lcol;
    const short* pb = T + (size_t)(n0 + w*8 + lrow)*768 + lcol;

    f32x4 acc[2][4] = {};

    #pragma unroll
    for(int i=0;i<2;i++){
        gload_lds16(pa + (size_t)(i*64)*768, &sh[(i*64 + w*8)*64]);
        gload_lds16(pb + (size_t)(i*64)*768, &sh[8192 + (i*64 + w*8)*64]);
    }
    int bb = 0;
    for(int kk=0; kk<12; kk++){
        if(kk<11){
            short* dstA = &sh[(bb^1)*16384];
            short* dstB = dstA + 8192;
            #pragma unroll
            for(int i=0;i<2;i++){
                gload_lds16(pa + (size_t)(i*64)*768 + (kk+1)*64, &dstA[(i*64 + w*8)*64]);
                gload_lds16(pb + (size_t)(i*64)*768 + (kk+1)*64, &dstB[(i*64 + w*8)*64]);
            }
            asm volatile("s_waitcnt vmcnt(4)" ::: "memory");
        } else {
            asm volatile("s_waitcnt vmcnt(0)" ::: "memory");
        }
        __builtin_amdgcn_s_barrier();
        asm volatile("" ::: "memory");

        const short* LA = &sh[bb*16384];
        const short* LB = LA + 8192;
        short8 af[2][2], bfv[4][2];
        #pragma unroll
        for(int mi=0; mi<2; mi++){
            int row = wm*32 + mi*16 + c;
            int rx = (row&7)<<3;
            af[mi][0] = *(const short8*)&LA[row*64 + ((g*8) ^ rx)];
            af[mi][1] = *(const short8*)&LA[row*64 + ((32 + g*8) ^ rx)];
        }
        #pragma unroll
        for(int ni=0; ni<4; ni++){
            int row = wn*64 + ni*16 + c;
            int rx = (row&7)<<3;
            bfv[ni][0] = *(const short8*)&LB[row*64 + ((g*8) ^ rx)];
            bfv[ni][1] = *(const short8*)&LB[row*64 + ((32 + g*8) ^ rx)];
        }
        __builtin_amdgcn_s_setprio(1);
        #pragma unroll
        for(int mi=0; mi<2; mi++)
            #pragma unroll
            for(int ni=0; ni<4; ni++){
                acc[mi][ni] = __builtin_amdgcn_mfma_f32_16x16x32_bf16(af[mi][0], bfv[ni][0], acc[mi][ni], 0,0,0);
                acc[mi][ni] = __builtin_amdgcn_mfma_f32_16x16x32_bf16(af[mi][1], bfv[ni][1], acc[mi][ni], 0,0,0);
            }
        __builtin_amdgcn_s_setprio(0);
        asm volatile("s_waitcnt lgkmcnt(0)" ::: "memory");
        __builtin_amdgcn_s_barrier();
        asm volatile("" ::: "memory");
        bb ^= 1;
    }

    if(mode==3){
        #pragma unroll
        for(int mi=0; mi<2; mi++) for(int ni=0; ni<4; ni++){
            #pragma unroll
            for(int r=0; r<4; r++){
                int m = m0 + wm*32 + mi*16 + g*4 + r;
                int n = n0 + wn*64 + ni*16 + c;
                if(m >= M_) continue;
                of[(size_t)m*768 + n] = acc[mi][ni][r] + bias[n];
            }
        }
        return;
    }

    if(seg==2){
        #pragma unroll
        for(int mi=0;mi<2;mi++)
            #pragma unroll
            for(int ni=0;ni<4;ni++){
                int nl_ = wn*64 + ni*16 + c;
                float bv = bias[nlb + nl_];
                s16x4 pk;
                #pragma unroll
                for(int r=0;r<4;r++) pk[r] = (short)f2bf(acc[mi][ni][r] + bv);
                int ml0 = wm*32 + mi*16 + g*4;
                *(s16x4*)&sh[nl_*LTS + ml0] = pk;       // transposed: [n][m]
            }
    } else {
        #pragma unroll
        for(int mi=0;mi<2;mi++)
            #pragma unroll
            for(int ni=0;ni<4;ni++){
                int nl_ = wn*64 + ni*16 + c;
                float bv = bias[nlb + nl_];
                #pragma unroll
                for(int r=0;r<4;r++){
                    int ml = wm*32 + mi*16 + g*4 + r;
                    sh[ml*LTS + nl_] = (short)f2bf(acc[mi][ni][r] + bv);
                }
            }
    }
    __syncthreads();

    #pragma unroll
    for(int i=0;i<4;i++){
        int idx = i*512 + t;
        int rp = idx>>4, ch = idx&15;
        short8 v8 = *(const short8*)&sh[rp*LTS + ch*8];
        if(seg==2){
            int nl = nlb + rp, hh = nl>>6, dd = nl&63;
            int mg = m0 + ch*8;
            if(mg < M_){
                int b0_ = mg/S_, s0 = mg - b0_*S_;
                if(s0+7 < S_ && mg+7 < M_){
                    *(short8*)&ovt[(((size_t)b0_*NH_+hh)*HD_+dd)*SKPAD + s0] = v8;
                } else {
                    for(int j=0;j<8;j++){
                        int m=mg+j;
                        if(m<M_){ int bj=m/S_, sj=m-bj*S_;
                            ovt[(((size_t)bj*NH_+hh)*HD_+dd)*SKPAD+sj]=v8[j]; }
                    }
                }
            }
        } else {
            int m = m0 + rp;
            if(m < M_){
                int b0_ = m/S_, s0 = m - b0_*S_;
                int nl = nlb + ch*8, hh = nl>>6, dd = nl&63;
                if(seg==1) *(short8*)&ok[(((size_t)b0_*NH_+hh)*SKPAD + s0)*HD_ + dd] = v8;
                else       *(short8*)&oq[(((size_t)b0_*NH_+hh)*S_   + s0)*HD_ + dd] = v8;
            }
        }
    }
}

// BARRIER-FREE flash attention: QBLK=128 (2 q-frags/wave), K/V fragments
// loaded directly from global (L1/L2-resident), P via per-wave LDS region.
// No __syncthreads anywhere in the kt loop -> free wave slip.
__global__ __launch_bounds__(256) void k_attn(
    const short* __restrict__ qh, const short* __restrict__ kh, const short* __restrict__ vt,
    short* __restrict__ ctx)
{
    __shared__ short lP[4*2048];
    const int t = threadIdx.x;
    const int w = t>>6, lane = t&63, g = lane>>4, c = lane&15;
    const int bh = blockIdx.x, b = bh/NH_, h = bh%NH_;
    const int q0 = blockIdx.y*128;

    // per-wave Q staging into own lP region (own-wave write->read: lgkmcnt only)
    #pragma unroll
    for(int i=0;i<4;i++){
        int row = i*8 + (lane>>3);
        int e8 = (lane&7)*8;
        int s = q0 + w*32 + row;
        short8 v = {};
        if(s < S_) v = *(const short8*)&qh[((size_t)bh*S_ + s)*HD_ + e8];
        *(short8*)&lP[w*2048 + row*64 + (e8 ^ ((row&7)<<3))] = v;
    }
    short8 qf[2][2];
    #pragma unroll
    for(int qi=0; qi<2; qi++)
        #pragma unroll
        for(int ks=0; ks<2; ks++)
            qf[qi][ks] = *(const short8*)&lP[w*2048 + (qi*16+c)*64 + ((ks*32+g*8) ^ ((c&7)<<3))];

    short8 ones;
    #pragma unroll
    for(int j=0;j<8;j++) ones[j] = (short)0x3F80;

    const short* Kb = kh + (size_t)bh*SKPAD*64 + (size_t)c*64 + g*8;
    const short* Vb = vt + (size_t)bh*64*SKPAD + (size_t)c*SKPAD + g*8;

    float m_run[2][4], l_run[2][4];
    f32x4 O[2][4] = {};
    #pragma unroll
    for(int qi=0;qi<2;qi++)
        #pragma unroll
        for(int r=0;r<4;r++){ m_run[qi][r] = -3e38f; l_run[qi][r] = 0.f; }

    #pragma unroll 1
    for(int kt=0; kt<10; kt++){
        const int key0 = kt*64;
        // direct global fragment loads (rows stride 64/SKPAD, cols by g)
        short8 kf[4][2], vf[4][2];
        #pragma unroll
        for(int nt=0; nt<4; nt++){
            const short* kr = Kb + (size_t)(key0 + nt*16)*64;
            kf[nt][0] = *(const short8*)(kr);
            kf[nt][1] = *(const short8*)(kr + 32);
            const short* vr = Vb + (size_t)(nt*16)*SKPAD + key0;
            vf[nt][0] = *(const short8*)(vr);
            vf[nt][1] = *(const short8*)(vr + 32);
        }

        float sv[2][4][4];
        #pragma unroll
        for(int nt=0; nt<4; nt++){
            __builtin_amdgcn_s_setprio(1);
            #pragma unroll
            for(int qi=0; qi<2; qi++){
                f32x4 sa = {};
                sa = __builtin_amdgcn_mfma_f32_16x16x32_bf16(qf[qi][0], kf[nt][0], sa, 0,0,0);
                sa = __builtin_amdgcn_mfma_f32_16x16x32_bf16(qf[qi][1], kf[nt][1], sa, 0,0,0);
                #pragma unroll
                for(int r=0;r<4;r++) sv[qi][nt][r] = sa[r]*0.18033688011f;  // /8 * log2(e)
            }
            __builtin_amdgcn_s_setprio(0);
        }
        if(kt==9){
            #pragma unroll
            for(int nt=0; nt<4; nt++){
                int key = 576 + nt*16 + c;
                if(key >= S_){
                    #pragma unroll
                    for(int qi=0;qi<2;qi++)
                        #pragma unroll
                        for(int r=0;r<4;r++) sv[qi][nt][r] = -3e38f;
                }
            }
        }
        float fac[2][4];
        #pragma unroll
        for(int qi=0; qi<2; qi++)
            #pragma unroll
            for(int r=0;r<4;r++){
                float mx = fmaxf(fmaxf(sv[qi][0][r],sv[qi][1][r]),fmaxf(sv[qi][2][r],sv[qi][3][r]));
                for(int off=1; off<16; off<<=1) mx = fmaxf(mx, __shfl_xor(mx, off));
                float nm = fmaxf(m_run[qi][r], mx);
                fac[qi][r] = __builtin_amdgcn_exp2f(m_run[qi][r] - nm);
                m_run[qi][r] = nm;
            }
        #pragma unroll
        for(int qi=0; qi<2; qi++)
            #pragma unroll
            for(int nt=0; nt<4; nt++)
                #pragma unroll
                for(int r=0;r<4;r++){
                    float p = __builtin_amdgcn_exp2f(sv[qi][nt][r] - m_run[qi][r]);
                    int prow = g*4 + r;
                    lP[w*2048 + qi*1024 + prow*64 + ((nt*16 + c) ^ ((prow&7)<<3))] = (short)f2bf(p);
                }
        short8 pf[2][2];
        #pragma unroll
        for(int qi=0; qi<2; qi++)
            #pragma unroll
            for(int ks=0; ks<2; ks++)
                pf[qi][ks] = *(const short8*)&lP[w*2048 + qi*1024 + c*64 + ((ks*32+g*8) ^ ((c&7)<<3))];
        __builtin_amdgcn_s_setprio(1);
        #pragma unroll
        for(int qi=0; qi<2; qi++){
            f32x4 rs = {};
            rs = __builtin_amdgcn_mfma_f32_16x16x32_bf16(pf[qi][0], ones, rs, 0,0,0);
            rs = __builtin_amdgcn_mfma_f32_16x16x32_bf16(pf[qi][1], ones, rs, 0,0,0);
            #pragma unroll
            for(int r=0;r<4;r++) l_run[qi][r] = l_run[qi][r]*fac[qi][r] + rs[r];
        }
        __builtin_amdgcn_s_setprio(0);
        #pragma unroll
        for(int qi=0; qi<2; qi++)
            #pragma unroll
            for(int nt=0;nt<4;nt++)
                #pragma unroll
                for(int r=0;r<4;r++) O[qi][nt][r] *= fac[qi][r];

        __builtin_amdgcn_s_setprio(1);
        #pragma unroll
        for(int nt=0; nt<4; nt++)
            #pragma unroll
            for(int qi=0; qi<2; qi++){
                O[qi][nt] = __builtin_amdgcn_mfma_f32_16x16x32_bf16(pf[qi][0], vf[nt][0], O[qi][nt], 0,0,0);
                O[qi][nt] = __builtin_amdgcn_mfma_f32_16x16x32_bf16(pf[qi][1], vf[nt][1], O[qi][nt], 0,0,0);
            }
        __builtin_amdgcn_s_setprio(0);
    }

    #pragma unroll
    for(int qi=0; qi<2; qi++)
        #pragma unroll
        for(int nt=0; nt<4; nt++)
            #pragma unroll
            for(int r=0;r<4;r++){
                int s = q0 + w*32 + qi*16 + g*4 + r;
                if(s < S_){
                    float val = O[qi][nt][r] / l_run[qi][r];
                    ctx[((size_t)b*S_ + s)*H_ + h*HD_ + nt*16 + c] = (short)f2bf(val);
                }
            }
}

extern "C" void kernel_launch(void* const* d_in, const int* in_sizes, int n_in,
                              void* d_out, int out_size, void* d_ws, size_t ws_size,
                              hipStream_t stream)
{
    const float* hs = (const float*)d_in[0];
    const float* Wq = (const float*)d_in[1];
    const float* bq = (const float*)d_in[2];
    const float* Wk = (const float*)d_in[3];
    const float* bk = (const float*)d_in[4];
    const float* Wv = (const float*)d_in[5];
    const float* bv = (const float*)d_in[6];
    const float* Wo = (const float*)d_in[7];
    const float* bo = (const float*)d_in[8];
    float* out = (float*)d_out;

    char* ws = (char*)d_ws;
    short* abf = (short*)(ws);
    short* ctx = abf;                               // reuse after QKV GEMM
    short* wqt = (short*)(ws + 7274496);
    short* wkt = (short*)(ws + 7274496 + 1179648);
    short* wvt = (short*)(ws + 7274496 + 2*1179648);
    short* wot = (short*)(ws + 7274496 + 3*1179648);
    short* qh  = (short*)(ws + 11993088);
    short* kh  = (short*)(ws + 19083264);
    short* vt  = (short*)(ws + 26947584);
    // total: 34,811,904 B

    k_prep<<<2733, 256, 0, stream>>>(hs, abf, Wq,Wk,Wv,Wo, wqt,wkt,wvt,wot, kh, vt);
    k_gemm<<<666, 512, 0, stream>>>(abf, wqt, bq,bk,bv, qh,kh,vt, nullptr, 0, 18);
    k_attn<<<dim3(96,5), 256, 0, stream>>>(qh, kh, vt, ctx);
    k_gemm<<<222, 512, 0, stream>>>(ctx, wot, bo,bo,bo, nullptr,nullptr,nullptr, out, 3, 6);
}

// Round 13
// 100.158 us; speedup vs baseline: 1.0216x; 1.0215x over previous
//
#include <hip/hip_runtime.h>
#include <hip/hip_bf16.h>

// out = softmax((X Wq + bq)(X Wk + bk)^T / 8) (X Wv + bv) Wo + bo
// All prune/straight-through ops in the reference are value-wise identity.
//
//   k_prep: fused {hs->bf16 A | W^T bf16 x4 | kh/vt pad zero}  (round-6 proven)
//   k_qkv : fused QKV GEMM, 256x256 tile, 8 waves (wave=128x64), BK=32,
//           TRIPLE-slot LDS, 4 phases/K-tile, COUNTED vmcnt(4) once per tile
//           (never 0 in main loop; tile kt+2's loads in flight across barriers).
//           r10-proven chunked epilogue (V transposed, 16B stores).
//   k_attn: flash attention (round-6 proven: QBLK=128, K/V dbuf gload_lds,
//           counted vmcnt, XCD-pinned, exp2 softmax, MFMA row-sum, setprio)
//   k_gemm: out-proj 128^2 512-thr dbuf (round-6 proven), fp32 out

#define B_ 8
#define S_ 577
#define H_ 768
#define NH_ 12
#define HD_ 64
#define M_ (B_*S_)     /* 4616 */
#define MPAD 4736
#define BH_ (B_*NH_)   /* 96 */
#define SKPAD 640      /* padded key count */
#define LTS 136        /* padded LDS row stride (128-tile epilogue) */
#define LTS2 264       /* padded LDS row stride (256-tile epilogue chunks) */

typedef __attribute__((ext_vector_type(8))) short short8;
typedef __attribute__((ext_vector_type(4))) short s16x4;
typedef __attribute__((ext_vector_type(4))) float f32x4;

__device__ inline unsigned short f2bf(float f){
    unsigned int u = __float_as_uint(f);
    u = u + 0x7fffu + ((u>>16)&1u);     // round-to-nearest-even
    return (unsigned short)(u>>16);
}

__device__ inline void gload_lds16(const short* g, short* l){
    __builtin_amdgcn_global_load_lds((const __attribute__((address_space(1))) void*)g,
                                     (__attribute__((address_space(3))) void*)l, 16, 0, 0);
}

// fused prep: blocks [0,1776) cvt | [1776,2352) wt | [2352,2733) pad
__global__ __launch_bounds__(256) void k_prep(
    const float* __restrict__ hs, short* __restrict__ abf,
    const float* __restrict__ Wq, const float* __restrict__ Wk,
    const float* __restrict__ Wv, const float* __restrict__ Wo,
    short* __restrict__ Tq, short* __restrict__ Tk,
    short* __restrict__ Tv, short* __restrict__ To,
    short* __restrict__ kh, short* __restrict__ vt)
{
    const int bid = blockIdx.x, t = threadIdx.x;
    if(bid < 1776){
        int i = bid*256 + t;
        if(bid >= 1731){ *(short8*)(abf + (size_t)i*8) = (short8){}; return; }
        const float4* p = (const float4*)(hs + (size_t)i*8);
        float4 a = p[0], b = p[1];
        short8 v;
        v[0]=(short)f2bf(a.x); v[1]=(short)f2bf(a.y); v[2]=(short)f2bf(a.z); v[3]=(short)f2bf(a.w);
        v[4]=(short)f2bf(b.x); v[5]=(short)f2bf(b.y); v[6]=(short)f2bf(b.z); v[7]=(short)f2bf(b.w);
        *(short8*)(abf + (size_t)i*8) = v;
    } else if(bid < 2352){
        int zidx = bid - 1776;
        int z = zidx & 3, rem = zidx >> 2;
        int kx = rem % 12, ny = rem / 12;
        const float* W = z==0?Wq: z==1?Wk: z==2?Wv:Wo;
        short*       T = z==0?Tq: z==1?Tk: z==2?Tv:To;
        __shared__ float lds[64][65];
        int k0 = kx*64, n0 = ny*64;
        for(int i=0;i<4;i++){
            int row = i*16 + (t>>4);
            int col = (t&15)*4;
            float4 v = *(const float4*)&W[(k0+row)*768 + n0 + col];
            lds[row][col]=v.x; lds[row][col+1]=v.y; lds[row][col+2]=v.z; lds[row][col+3]=v.w;
        }
        __syncthreads();
        for(int i=0;i<4;i++){
            int n = i*16 + (t>>4);
            int k4 = (t&15)*4;
            for(int j=0;j<4;j++)
                T[(n0+n)*768 + k0 + k4 + j] = (short)f2bf(lds[k4+j][n]);
        }
    } else {
        int tid = (bid-2352)*256 + t;
        short8 z = {};
        if(tid < 48384){
            int row_id = tid>>3, ch = tid&7;
            int bh = row_id/63, r = row_id - bh*63;
            *(short8*)&kh[((size_t)bh*SKPAD + 577 + r)*64 + ch*8] = z;
        } else if(tid < 97536){
            int j = tid - 48384;
            int row_id = j>>3, ch = j&7;
            int bh = row_id>>6, d = row_id&63;
            *(short8*)&vt[((size_t)bh*64 + d)*SKPAD + 576 + ch*8] = z;
        }
    }
}

// ------- fused QKV: 256x256, 8 waves (128x64/wave), BK=32, 3-slot counted -----
__global__ __launch_bounds__(512) void k_qkv(
    const short* __restrict__ A, const short* __restrict__ T,
    const float* __restrict__ b0, const float* __restrict__ b1, const float* __restrict__ b2,
    short* __restrict__ oq, short* __restrict__ ok, short* __restrict__ ovt)
{
    __shared__ short sh[49152];   // 96KB: 3 slots x (A 16KB | B 16KB)
    const int t = threadIdx.x;

    // bijective XCD-chunked swizzle, NT=9 n-tiles
    const int nwg = gridDim.x;
    const int q8 = nwg>>3, r8 = nwg&7;
    const int xcd = blockIdx.x&7, cidx = blockIdx.x>>3;
    const int wg = (xcd<r8 ? xcd*(q8+1) : r8*(q8+1) + (xcd-r8)*q8) + cidx;
    const int mt = wg/9, nt9 = wg - mt*9;
    const int m0 = mt*256, n0 = nt9*256;
    const int seg = n0/768;
    const float* bias = (seg==0?b0: seg==1?b1:b2);
    const int nlb = n0 - seg*768;

    const int w = t>>6, lane = t&63, g = lane>>4, c = lane&15;
    const int wm = w>>2, wn = w&3;       // wave tile: rows wm*128.., cols wn*64..

    // staging: 4 loads/thread/tile (A j0,j1 | B j0,j1); BK=32 -> row = cid>>2,
    // chunk = cid&3; source chunk XOR (row>>1)&3 -> 2-way-free ds_read banks
    const short *gA0,*gA1,*gB0,*gB1; int dA0,dA1,dB0,dB1;
    {
        int cid0 = t,      r0 = cid0>>2, c0 = cid0&3;
        int cid1 = 512+t,  r1 = cid1>>2, c1 = cid1&3;
        int rga0 = m0+r0; if(rga0>4735) rga0 = 4735;
        int rga1 = m0+r1; if(rga1>4735) rga1 = 4735;
        gA0 = A + (size_t)rga0*768 + (c0 ^ ((r0>>1)&3))*8;
        gA1 = A + (size_t)rga1*768 + (c1 ^ ((r1>>1)&3))*8;
        gB0 = T + (size_t)(n0+r0)*768 + (c0 ^ ((r0>>1)&3))*8;
        gB1 = T + (size_t)(n0+r1)*768 + (c1 ^ ((r1>>1)&3))*8;
        dA0 = r0*32 + c0*8; dA1 = r1*32 + c1*8;
        dB0 = 8192 + dA0;   dB1 = 8192 + dA1;
    }
    #define SLOT(tt) (((tt)%3)*16384)
    #define ISSA0(tt) gload_lds16(gA0 + (tt)*32, &sh[SLOT(tt) + dA0])
    #define ISSA1(tt) gload_lds16(gA1 + (tt)*32, &sh[SLOT(tt) + dA1])
    #define ISSB0(tt) gload_lds16(gB0 + (tt)*32, &sh[SLOT(tt) + dB0])
    #define ISSB1(tt) gload_lds16(gB1 + (tt)*32, &sh[SLOT(tt) + dB1])

    f32x4 acc[8][4] = {};

    // prologue: stage tiles 0,1 fully; counted wait for tile 0 only
    ISSA0(0); ISSA1(0); ISSB0(0); ISSB1(0);
    ISSA0(1); ISSA1(1); ISSB0(1); ISSB1(1);
    asm volatile("s_waitcnt vmcnt(4)" ::: "memory");
    __builtin_amdgcn_s_barrier();
    asm volatile("" ::: "memory");

    for(int kt=0; kt<24; kt++){
        const short* LA = &sh[SLOT(kt)];
        const short* LB = LA + 8192;
        short8 a[4], a2[4], b[4];

        // ---- phase 1: a0-3 + b0-1 reads; issue A j0 of kt+2 ----
        #pragma unroll
        for(int mi=0; mi<4; mi++){
            int row = wm*128 + mi*16 + c;
            a[mi] = *(const short8*)&LA[row*32 + ((g ^ ((row>>1)&3))<<3)];
        }
        #pragma unroll
        for(int ni=0; ni<2; ni++){
            int row = wn*64 + ni*16 + c;
            b[ni] = *(const short8*)&LB[row*32 + ((g ^ ((row>>1)&3))<<3)];
        }
        if(kt<22) ISSA0(kt+2);
        __builtin_amdgcn_s_barrier();
        asm volatile("s_waitcnt lgkmcnt(0)" ::: "memory");
        __builtin_amdgcn_s_setprio(1);
        #pragma unroll
        for(int mi=0; mi<4; mi++)
            #pragma unroll
            for(int ni=0; ni<2; ni++)
                acc[mi][ni] = __builtin_amdgcn_mfma_f32_16x16x32_bf16(a[mi], b[ni], acc[mi][ni],0,0,0);
        __builtin_amdgcn_s_setprio(0);
        __builtin_amdgcn_s_barrier();
        asm volatile("" ::: "memory");

        // ---- phase 2: b2-3 reads; issue A j1 ----
        #pragma unroll
        for(int ni=2; ni<4; ni++){
            int row = wn*64 + ni*16 + c;
            b[ni] = *(const short8*)&LB[row*32 + ((g ^ ((row>>1)&3))<<3)];
        }
        if(kt<22) ISSA1(kt+2);
        __builtin_amdgcn_s_barrier();
        asm volatile("s_waitcnt lgkmcnt(0)" ::: "memory");
        __builtin_amdgcn_s_setprio(1);
        #pragma unroll
        for(int mi=0; mi<4; mi++)
            #pragma unroll
            for(int ni=2; ni<4; ni++)
                acc[mi][ni] = __builtin_amdgcn_mfma_f32_16x16x32_bf16(a[mi], b[ni], acc[mi][ni],0,0,0);
        __builtin_amdgcn_s_setprio(0);
        __builtin_amdgcn_s_barrier();
        asm volatile("" ::: "memory");

        // ---- phase 3: a4-7 reads; issue B j0 ----
        #pragma unroll
        for(int mi=0; mi<4; mi++){
            int row = wm*128 + 64 + mi*16 + c;
            a2[mi] = *(const short8*)&LA[row*32 + ((g ^ ((row>>1)&3))<<3)];
        }
        if(kt<22) ISSB0(kt+2);
        __builtin_amdgcn_s_barrier();
        asm volatile("s_waitcnt lgkmcnt(0)" ::: "memory");
        __builtin_amdgcn_s_setprio(1);
        #pragma unroll
        for(int mi=0; mi<4; mi++)
            #pragma unroll
            for(int ni=0; ni<2; ni++)
                acc[4+mi][ni] = __builtin_amdgcn_mfma_f32_16x16x32_bf16(a2[mi], b[ni], acc[4+mi][ni],0,0,0);
        __builtin_amdgcn_s_setprio(0);
        __builtin_amdgcn_s_barrier();
        asm volatile("" ::: "memory");

        // ---- phase 4: no reads; issue B j1; counted vmcnt; barrier ----
        if(kt<22) ISSB1(kt+2);
        __builtin_amdgcn_s_setprio(1);
        #pragma unroll
        for(int mi=0; mi<4; mi++)
            #pragma unroll
            for(int ni=2; ni<4; ni++)
                acc[4+mi][ni] = __builtin_amdgcn_mfma_f32_16x16x32_bf16(a2[mi], b[ni], acc[4+mi][ni],0,0,0);
        __builtin_amdgcn_s_setprio(0);
        if(kt<22){ asm volatile("s_waitcnt vmcnt(4)" ::: "memory"); }   // kt+1 staged; kt+2 in flight
        else     { asm volatile("s_waitcnt vmcnt(0)" ::: "memory"); }
        __builtin_amdgcn_s_barrier();
        asm volatile("" ::: "memory");
    }
    #undef SLOT
    #undef ISSA0
    #undef ISSA1
    #undef ISSB0
    #undef ISSB1

    // ---------------- epilogue: chunked LDS-staged coalesced stores (r10) ----
    if(seg==2){
        #pragma unroll
        for(int cch=0; cch<2; cch++){
            if((wn>>1) == cch){
                #pragma unroll
                for(int mi=0; mi<8; mi++)
                    #pragma unroll
                    for(int ni=0; ni<4; ni++){
                        int nc = (wn&1)*64 + ni*16 + c;
                        float bv = bias[nlb + cch*128 + nc];
                        s16x4 pk;
                        #pragma unroll
                        for(int r=0;r<4;r++) pk[r] = (short)f2bf(acc[mi][ni][r] + bv);
                        int ml0 = wm*128 + mi*16 + g*4;
                        *(s16x4*)&sh[nc*LTS2 + ml0] = pk;
                    }
            }
            __syncthreads();
            #pragma unroll
            for(int i=0;i<8;i++){
                int idx = i*512 + t;
                int rp = idx>>5, ch = idx&31;
                short8 v8 = *(const short8*)&sh[rp*LTS2 + ch*8];
                int nl = nlb + cch*128 + rp, hh = nl>>6, dd = nl&63;
                int mg = m0 + ch*8;
                if(mg < M_){
                    int bb = mg/S_, s0 = mg - bb*S_;
                    if(s0+7 < S_ && mg+7 < M_){
                        *(short8*)&ovt[(((size_t)bb*NH_+hh)*HD_+dd)*SKPAD + s0] = v8;
                    } else {
                        for(int j=0;j<8;j++){
                            int m=mg+j;
                            if(m<M_){ int bj=m/S_, sj=m-bj*S_;
                                ovt[(((size_t)bj*NH_+hh)*HD_+dd)*SKPAD+sj]=v8[j]; }
                        }
                    }
                }
            }
            __syncthreads();
        }
    } else {
        #pragma unroll
        for(int cch=0; cch<2; cch++){
            if(wm == cch){
                #pragma unroll
                for(int mi=0; mi<8; mi++)
                    #pragma unroll
                    for(int ni=0; ni<4; ni++){
                        int nl_ = wn*64 + ni*16 + c;
                        float bv = bias[nlb + nl_];
                        #pragma unroll
                        for(int r=0;r<4;r++){
                            int ml = mi*16 + g*4 + r;
                            sh[ml*LTS2 + nl_] = (short)f2bf(acc[mi][ni][r] + bv);
                        }
                    }
            }
            __syncthreads();
            #pragma unroll
            for(int i=0;i<8;i++){
                int idx = i*512 + t;
                int rp = idx>>5, ch = idx&31;
                short8 v8 = *(const short8*)&sh[rp*LTS2 + ch*8];
                int m = m0 + cch*128 + rp;
                if(m < M_){
                    int bb = m/S_, ss = m - bb*S_;
                    int nl = nlb + ch*8, hh = nl>>6, dd = nl&63;
                    if(seg==1) *(short8*)&ok[(((size_t)bb*NH_+hh)*SKPAD + ss)*HD_ + dd] = v8;
                    else       *(short8*)&oq[(((size_t)bb*NH_+hh)*S_   + ss)*HD_ + dd] = v8;
                }
            }
            __syncthreads();
        }
    }
}

// out-proj GEMM (round-6 proven): 128x128 tile, 512 thr, dbuf vmcnt(4)
__global__ __launch_bounds__(512) void k_gemm(
    const short* __restrict__ A, const short* __restrict__ T,
    const float* __restrict__ b0,
    float* __restrict__ of, int NT)
{
    __shared__ short sh[32768];
    const int t = threadIdx.x;

    const int nwg = gridDim.x;
    const int q8 = nwg>>3, r8 = nwg&7;
    const int xcd = blockIdx.x&7, cidx = blockIdx.x>>3;
    const int wg = (xcd<r8 ? xcd*(q8+1) : r8*(q8+1) + (xcd-r8)*q8) + cidx;
    const int mt = wg/NT, ntile = wg - mt*NT;
    const int m0 = mt*128, n0 = ntile*128;
    const float* bias = b0;

    const int w = t>>6, lane = t&63, g = lane>>4, c = lane&15;
    const int wm = w>>1, wn = w&1;

    const int lrow = lane>>3;
    const int lcol = ((lane&7) ^ lrow) * 8;
    const short* pa = A + (size_t)(m0 + w*8 + lrow)*768 + lcol;
    const short* pb = T + (size_t)(n0 + w*8 + lrow)*768 + lcol;

    f32x4 acc[2][4] = {};

    #pragma unroll
    for(int i=0;i<2;i++){
        gload_lds16(pa + (size_t)(i*64)*768, &sh[(i*64 + w*8)*64]);
        gload_lds16(pb + (size_t)(i*64)*768, &sh[8192 + (i*64 + w*8)*64]);
    }
    int bb = 0;
    for(int kk=0; kk<12; kk++){
        if(kk<11){
            short* dstA = &sh[(bb^1)*16384];
            short* dstB = dstA + 8192;
            #pragma unroll
            for(int i=0;i<2;i++){
                gload_lds16(pa + (size_t)(i*64)*768 + (kk+1)*64, &dstA[(i*64 + w*8)*64]);
                gload_lds16(pb + (size_t)(i*64)*768 + (kk+1)*64, &dstB[(i*64 + w*8)*64]);
            }
            asm volatile("s_waitcnt vmcnt(4)" ::: "memory");
        } else {
            asm volatile("s_waitcnt vmcnt(0)" ::: "memory");
        }
        __builtin_amdgcn_s_barrier();
        asm volatile("" ::: "memory");

        const short* LA = &sh[bb*16384];
        const short* LB = LA + 8192;
        short8 af[2][2], bfv[4][2];
        #pragma unroll
        for(int mi=0; mi<2; mi++){
            int row = wm*32 + mi*16 + c;
            int rx = (row&7)<<3;
            af[mi][0] = *(const short8*)&LA[row*64 + ((g*8) ^ rx)];
            af[mi][1] = *(const short8*)&LA[row*64 + ((32 + g*8) ^ rx)];
        }
        #pragma unroll
        for(int ni=0; ni<4; ni++){
            int row = wn*64 + ni*16 + c;
            int rx = (row&7)<<3;
            bfv[ni][0] = *(const short8*)&LB[row*64 + ((g*8) ^ rx)];
            bfv[ni][1] = *(const short8*)&LB[row*64 + ((32 + g*8) ^ rx)];
        }
        __builtin_amdgcn_s_setprio(1);
        #pragma unroll
        for(int mi=0; mi<2; mi++)
            #pragma unroll
            for(int ni=0; ni<4; ni++){
                acc[mi][ni] = __builtin_amdgcn_mfma_f32_16x16x32_bf16(af[mi][0], bfv[ni][0], acc[mi][ni], 0,0,0);
                acc[mi][ni] = __builtin_amdgcn_mfma_f32_16x16x32_bf16(af[mi][1], bfv[ni][1], acc[mi][ni], 0,0,0);
            }
        __builtin_amdgcn_s_setprio(0);
        asm volatile("s_waitcnt lgkmcnt(0)" ::: "memory");
        __builtin_amdgcn_s_barrier();
        asm volatile("" ::: "memory");
        bb ^= 1;
    }

    #pragma unroll
    for(int mi=0; mi<2; mi++) for(int ni=0; ni<4; ni++){
        #pragma unroll
        for(int r=0; r<4; r++){
            int m = m0 + wm*32 + mi*16 + g*4 + r;
            int n = n0 + wn*64 + ni*16 + c;
            if(m >= M_) continue;
            of[(size_t)m*768 + n] = acc[mi][ni][r] + bias[n];
        }
    }
}

// flash attention (round-6 proven): QBLK=128, K/V dbuf counted vmcnt, setprio
__global__ __launch_bounds__(256) void k_attn(
    const short* __restrict__ qh, const short* __restrict__ kh, const short* __restrict__ vt,
    short* __restrict__ ctx)
{
    __shared__ short lK[2][64*64], lV[2][64*64], lP[4*2048];
    const int t = threadIdx.x;
    const int w = t>>6, lane = t&63, g = lane>>4, c = lane&15;
    const int bh = blockIdx.x, b = bh/NH_, h = bh%NH_;
    const int q0 = blockIdx.y*128;

    #pragma unroll
    for(int i=0;i<4;i++){
        int row = i*8 + (lane>>3);
        int e8 = (lane&7)*8;
        int s = q0 + w*32 + row;
        short8 v = {};
        if(s < S_) v = *(const short8*)&qh[((size_t)bh*S_ + s)*HD_ + e8];
        *(short8*)&lP[w*2048 + row*64 + (e8 ^ ((row&7)<<3))] = v;
    }
    short8 qf[2][2];
    #pragma unroll
    for(int qi=0; qi<2; qi++)
        #pragma unroll
        for(int ks=0; ks<2; ks++)
            qf[qi][ks] = *(const short8*)&lP[w*2048 + (qi*16+c)*64 + ((ks*32+g*8) ^ ((c&7)<<3))];

    short8 ones;
    #pragma unroll
    for(int j=0;j<8;j++) ones[j] = (short)0x3F80;

    const int srow = lane>>3;
    const int sw8 = ((lane&7) ^ srow)*8;
    const short* pk0 = kh + ((size_t)bh*SKPAD + w*16 + srow)*64 + sw8;
    const short* pv0 = vt + ((size_t)bh*64 + w*16 + srow)*SKPAD + sw8;

    #pragma unroll
    for(int i=0;i<2;i++){
        gload_lds16(pk0 + i*8*64,    &lK[0][(w*16+i*8)*64]);
        gload_lds16(pv0 + i*8*SKPAD, &lV[0][(w*16+i*8)*64]);
    }

    float m_run[2][4], l_run[2][4];
    f32x4 O[2][4] = {};
    #pragma unroll
    for(int qi=0;qi<2;qi++)
        #pragma unroll
        for(int r=0;r<4;r++){ m_run[qi][r] = -3e38f; l_run[qi][r] = 0.f; }

    int bb = 0;
    for(int kt=0; kt<10; kt++){
        if(kt<9){
            const short* pk = pk0 + (kt+1)*4096;
            const short* pv = pv0 + (kt+1)*64;
            #pragma unroll
            for(int i=0;i<2;i++){
                gload_lds16(pk + i*8*64,    &lK[bb^1][(w*16+i*8)*64]);
                gload_lds16(pv + i*8*SKPAD, &lV[bb^1][(w*16+i*8)*64]);
            }
            asm volatile("s_waitcnt vmcnt(4)" ::: "memory");
        } else {
            asm volatile("s_waitcnt vmcnt(0)" ::: "memory");
        }
        __builtin_amdgcn_s_barrier();
        asm volatile("" ::: "memory");

        const short* LK = lK[bb]; const short* LV = lV[bb];

        float sv[2][4][4];
        #pragma unroll
        for(int nt=0; nt<4; nt++){
            int row = nt*16 + c;
            int rx = (row&7)<<3;
            short8 kf[2];
            kf[0] = *(const short8*)&LK[row*64 + ((g*8) ^ rx)];
            kf[1] = *(const short8*)&LK[row*64 + ((32+g*8) ^ rx)];
            __builtin_amdgcn_s_setprio(1);
            #pragma unroll
            for(int qi=0; qi<2; qi++){
                f32x4 sa = {};
                sa = __builtin_amdgcn_mfma_f32_16x16x32_bf16(qf[qi][0], kf[0], sa, 0,0,0);
                sa = __builtin_amdgcn_mfma_f32_16x16x32_bf16(qf[qi][1], kf[1], sa, 0,0,0);
                #pragma unroll
                for(int r=0;r<4;r++) sv[qi][nt][r] = sa[r]*0.18033688011f;
            }
            __builtin_amdgcn_s_setprio(0);
        }
        if(kt==9){
            #pragma unroll
            for(int nt=0; nt<4; nt++){
                int key = 576 + nt*16 + c;
                if(key >= S_){
                    #pragma unroll
                    for(int qi=0;qi<2;qi++)
                        #pragma unroll
                        for(int r=0;r<4;r++) sv[qi][nt][r] = -3e38f;
                }
            }
        }
        float fac[2][4];
        #pragma unroll
        for(int qi=0; qi<2; qi++)
            #pragma unroll
            for(int r=0;r<4;r++){
                float mx = fmaxf(fmaxf(sv[qi][0][r],sv[qi][1][r]),fmaxf(sv[qi][2][r],sv[qi][3][r]));
                for(int off=1; off<16; off<<=1) mx = fmaxf(mx, __shfl_xor(mx, off));
                float nm = fmaxf(m_run[qi][r], mx);
                fac[qi][r] = __builtin_amdgcn_exp2f(m_run[qi][r] - nm);
                m_run[qi][r] = nm;
            }
        #pragma unroll
        for(int qi=0; qi<2; qi++)
            #pragma unroll
            for(int nt=0; nt<4; nt++)
                #pragma unroll
                for(int r=0;r<4;r++){
                    float p = __builtin_amdgcn_exp2f(sv[qi][nt][r] - m_run[qi][r]);
                    int prow = g*4 + r;
                    lP[w*2048 + qi*1024 + prow*64 + ((nt*16 + c) ^ ((prow&7)<<3))] = (short)f2bf(p);
                }
        short8 pf[2][2];
        #pragma unroll
        for(int qi=0; qi<2; qi++)
            #pragma unroll
            for(int ks=0; ks<2; ks++)
                pf[qi][ks] = *(const short8*)&lP[w*2048 + qi*1024 + c*64 + ((ks*32+g*8) ^ ((c&7)<<3))];
        __builtin_amdgcn_s_setprio(1);
        #pragma unroll
        for(int qi=0; qi<2; qi++){
            f32x4 rs = {};
            rs = __builtin_amdgcn_mfma_f32_16x16x32_bf16(pf[qi][0], ones, rs, 0,0,0);
            rs = __builtin_amdgcn_mfma_f32_16x16x32_bf16(pf[qi][1], ones, rs, 0,0,0);
            #pragma unroll
            for(int r=0;r<4;r++) l_run[qi][r] = l_run[qi][r]*fac[qi][r] + rs[r];
        }
        __builtin_amdgcn_s_setprio(0);
        #pragma unroll
        for(int qi=0; qi<2; qi++)
            #pragma unroll
            for(int nt=0;nt<4;nt++)
                #pragma unroll
                for(int r=0;r<4;r++) O[qi][nt][r] *= fac[qi][r];

        __builtin_amdgcn_s_setprio(1);
        #pragma unroll
        for(int nt=0; nt<4; nt++){
            int vrow = nt*16 + c;
            int rx = (vrow&7)<<3;
            short8 vf[2];
            vf[0] = *(const short8*)&LV[vrow*64 + ((g*8) ^ rx)];
            vf[1] = *(const short8*)&LV[vrow*64 + ((32+g*8) ^ rx)];
            #pragma unroll
            for(int qi=0; qi<2; qi++){
                O[qi][nt] = __builtin_amdgcn_mfma_f32_16x16x32_bf16(pf[qi][0], vf[0], O[qi][nt], 0,0,0);
                O[qi][nt] = __builtin_amdgcn_mfma_f32_16x16x32_bf16(pf[qi][1], vf[1], O[qi][nt], 0,0,0);
            }
        }
        __builtin_amdgcn_s_setprio(0);
        asm volatile("s_waitcnt lgkmcnt(0)" ::: "memory");
        __builtin_amdgcn_s_barrier();
        asm volatile("" ::: "memory");
        bb ^= 1;
    }

    #pragma unroll
    for(int qi=0; qi<2; qi++)
        #pragma unroll
        for(int nt=0; nt<4; nt++)
            #pragma unroll
            for(int r=0;r<4;r++){
                int s = q0 + w*32 + qi*16 + g*4 + r;
                if(s < S_){
                    float val = O[qi][nt][r] / l_run[qi][r];
                    ctx[((size_t)b*S_ + s)*H_ + h*HD_ + nt*16 + c] = (short)f2bf(val);
                }
            }
}

extern "C" void kernel_launch(void* const* d_in, const int* in_sizes, int n_in,
                              void* d_out, int out_size, void* d_ws, size_t ws_size,
                              hipStream_t stream)
{
    const float* hs = (const float*)d_in[0];
    const float* Wq = (const float*)d_in[1];
    const float* bq = (const float*)d_in[2];
    const float* Wk = (const float*)d_in[3];
    const float* bk = (const float*)d_in[4];
    const float* Wv = (const float*)d_in[5];
    const float* bv = (const float*)d_in[6];
    const float* Wo = (const float*)d_in[7];
    const float* bo = (const float*)d_in[8];
    float* out = (float*)d_out;

    char* ws = (char*)d_ws;
    short* abf = (short*)(ws);
    short* ctx = abf;                               // reuse after QKV GEMM
    short* wqt = (short*)(ws + 7274496);
    short* wkt = (short*)(ws + 7274496 + 1179648);
    short* wvt = (short*)(ws + 7274496 + 2*1179648);
    short* wot = (short*)(ws + 7274496 + 3*1179648);
    short* qh  = (short*)(ws + 11993088);
    short* kh  = (short*)(ws + 19083264);
    short* vt  = (short*)(ws + 26947584);
    // total: 34,811,904 B

    k_prep<<<2733, 256, 0, stream>>>(hs, abf, Wq,Wk,Wv,Wo, wqt,wkt,wvt,wot, kh, vt);
    k_qkv<<<171, 512, 0, stream>>>(abf, wqt, bq,bk,bv, qh,kh,vt);
    k_attn<<<dim3(96,5), 256, 0, stream>>>(qh, kh, vt, ctx);
    k_gemm<<<222, 512, 0, stream>>>(ctx, wot, bo, out, 6);
}